// Round 2
// 937.327 us; speedup vs baseline: 1.1631x; 1.1631x over previous
//
#include <hip/hip_runtime.h>
#include <cstdio>
#include <cstdint>
#include <cstddef>

#define AS_GLOBAL __attribute__((address_space(1)))
#define AS_LDS    __attribute__((address_space(3)))

typedef __bf16 bf16x8 __attribute__((ext_vector_type(8)));
typedef float  f32x4  __attribute__((ext_vector_type(4)));

constexpr int OUT_F = 4096;
constexpr int IN_F  = 4096;
constexpr int MROWS = 8 * 2048;   // B*S = 16384

// ---------------------------------------------------------------------------
// Kernel 1: dequantize W_q (int32 u8 values, shape [64][262144] row-major)
// into bf16 W[o][i] row-major [4096][4096].  (unchanged — verified)
// ---------------------------------------------------------------------------
__global__ void dequant_w(const int* __restrict__ Wq, const float* __restrict__ scale,
                          const float* __restrict__ zero, __bf16* __restrict__ Wb) {
    int t   = blockIdx.x * blockDim.x + threadIdx.x;
    int idx = t * 4;                       // flat index into W[o][i]
    int o   = idx >> 12;
    int i   = idx & 4095;
    int n   = ((o & 63) << 12) | i;        // group index
    size_t flat = ((size_t)(o >> 6) << 18) + (size_t)n;
    int4   q = *(const int4*)(Wq + flat);
    float4 z = *(const float4*)(zero + n);
    float4 s = *(const float4*)(scale + n);
    __bf16 r[4];
    r[0] = (__bf16)(((float)q.x - z.x) * s.x);
    r[1] = (__bf16)(((float)q.y - z.y) * s.y);
    r[2] = (__bf16)(((float)q.z - z.z) * s.z);
    r[3] = (__bf16)(((float)q.w - z.w) * s.w);
    *(uint2*)(Wb + idx) = *(const uint2*)r;
}

// ---------------------------------------------------------------------------
// Kernel 2: x fp32 -> bf16  (unchanged)
// ---------------------------------------------------------------------------
__global__ void convert_x(const float* __restrict__ x, __bf16* __restrict__ xb) {
    size_t t   = (size_t)blockIdx.x * blockDim.x + threadIdx.x;
    size_t idx = t * 8;
    float4 a = *(const float4*)(x + idx);
    float4 b = *(const float4*)(x + idx + 4);
    __bf16 r[8];
    r[0] = (__bf16)a.x; r[1] = (__bf16)a.y; r[2] = (__bf16)a.z; r[3] = (__bf16)a.w;
    r[4] = (__bf16)b.x; r[5] = (__bf16)b.y; r[6] = (__bf16)b.z; r[7] = (__bf16)b.w;
    *(uint4*)(xb + idx) = *(const uint4*)r;
}

// ---------------------------------------------------------------------------
// Kernel 3: C[M][N] = A[M][K] * B[N][K]^T + bias   (bf16 in, fp32 out)
//
// 256x256 tile, BK=32, 512 threads (8 waves, 2M x 4N), per-wave 128x64 C.
// 4-deep LDS pipeline (4 x 32KB buffers = 128 KiB STATIC shared — no
// dynamic-LDS attribute call, which is graph-capture-unsafe), staged 3
// K-tiles ahead via global_load_lds width=16. Counted vmcnt(8) per tile —
// loads stay in flight across barriers; never drained to 0 in the main
// loop (T3+T4). Raw s_barrier (1 per K-step, 32 MFMA/wave/barrier),
// setprio around the MFMA cluster (T5).
//
// LDS layout (both A and B): 16 subtiles of 1 KiB, subtile s = rows
// [s*16, s*16+16) x 32 k. Within subtile, 16B chunk (row, c) stored at slot
// row*4 + (c ^ ((row>>1)&3))  — swizzle applied on BOTH the (pre-permuted)
// global source address (global_load_lds writes linearly, rule #21) and the
// ds_read address. Fragment read (16 rows @ fixed chunk) then hits each
// bank exactly 8x/wave with balanced slots -> conflict-free ds_read_b128.
//
// Race-freedom (per-tile invariant at entry of tile T): tiles <= T landed,
// T+1/T+2 in flight. Body issues STAGE(T+3) into buffer (T+3)&3, whose
// last reader was tile T-1, separated by the end-of-(T-1) barrier.
// End-of-tile vmcnt(8) retires this wave's tile-(T+1) loads; the barrier
// publishes the invariant cross-wave (every wave waits its own loads).
// ---------------------------------------------------------------------------
__device__ __forceinline__ void load16_to_lds(const void* g, void* lds) {
    __builtin_amdgcn_global_load_lds((AS_GLOBAL void*)g, (AS_LDS void*)lds, 16, 0, 0);
}

__global__ __launch_bounds__(512, 2) void gemm256(
    const __bf16* __restrict__ A,   // [M][K]
    const __bf16* __restrict__ B,   // [N][K]
    const float*  __restrict__ bias,
    float*        __restrict__ C)   // [M][N]
{
    constexpr int K   = IN_F, N = OUT_F;
    constexpr int BK  = 32;
    constexpr int NT  = K / BK;        // 128 K-tiles
    constexpr int BUF = 32768;         // bytes per pipeline buffer (A 16K + B 16K)
    __shared__ __align__(16) char smem[4 * BUF];   // 128 KiB static

    const int tid = threadIdx.x;
    const int l   = tid & 63;
    const int w   = tid >> 6;          // wave 0..7
    const int wr  = w >> 2;            // wave row 0..1  (128 rows each)
    const int wc  = w & 3;             // wave col 0..3  (64 cols each)

    // T1: bijective XCD swizzle. 1024 blocks, 8 XCDs -> 128 contiguous wgids
    // per XCD; n-fastest so the 2MB A-tile stays L2-resident per 16-ntile sweep.
    const int bid = blockIdx.x;
    const int wg  = (bid & 7) * 128 + (bid >> 3);
    const int n0  = (wg & 15) * 256;
    const int m0  = (wg >> 4) * 256;

    // ---- staging source (inverse-swizzled global address) ----
    // wave w fills subtiles {2w, 2w+1} of A and of B each tile (4 loads/thread).
    // phys slot l -> logical row l>>2, chunk (l&3)^((l>>3)&3).
    const int srow   = l >> 2;
    const int schunk = (l & 3) ^ ((l >> 3) & 3);
    const __bf16* sA0 = A + (size_t)(m0 + (w*2+0)*16 + srow) * K + schunk*8;
    const __bf16* sA1 = A + (size_t)(m0 + (w*2+1)*16 + srow) * K + schunk*8;
    const __bf16* sB0 = B + (size_t)(n0 + (w*2+0)*16 + srow) * K + schunk*8;
    const __bf16* sB1 = B + (size_t)(n0 + (w*2+1)*16 + srow) * K + schunk*8;
    const int dstA0 = (w*2+0)*1024, dstA1 = (w*2+1)*1024;
    const int dstB0 = 16384 + dstA0, dstB1 = 16384 + dstA1;

    // ---- fragment read offset (swizzled): lane holds X[row=l&15][k=(l>>4)*8+j]
    const int fr = l & 15, fg = l >> 4;
    const int in_off = fr*64 + ((fg ^ ((fr >> 1) & 3)) << 4);

    f32x4 acc[8][4] = {};

#define STAGE(t) do {                                                   \
        char* _b = smem + ((t) & 3) * BUF;                              \
        const int _k = (t) * BK;                                        \
        load16_to_lds(sA0 + _k, _b + dstA0);                            \
        load16_to_lds(sA1 + _k, _b + dstA1);                            \
        load16_to_lds(sB0 + _k, _b + dstB0);                            \
        load16_to_lds(sB1 + _k, _b + dstB1);                            \
    } while (0)

#define COMPUTE(t) do {                                                 \
        const char* _a  = smem + ((t) & 3) * BUF;                       \
        const char* _bb = _a + 16384;                                   \
        bf16x8 aF[8], bF[4];                                            \
        _Pragma("unroll")                                               \
        for (int mi = 0; mi < 8; ++mi)                                  \
            aF[mi] = *(const bf16x8*)(_a + (wr*8 + mi)*1024 + in_off);  \
        _Pragma("unroll")                                               \
        for (int ni = 0; ni < 4; ++ni)                                  \
            bF[ni] = *(const bf16x8*)(_bb + (wc*4 + ni)*1024 + in_off); \
        __builtin_amdgcn_s_setprio(1);                                  \
        _Pragma("unroll")                                               \
        for (int mi = 0; mi < 8; ++mi)                                  \
            _Pragma("unroll")                                           \
            for (int ni = 0; ni < 4; ++ni)                              \
                acc[mi][ni] = __builtin_amdgcn_mfma_f32_16x16x32_bf16(  \
                    aF[mi], bF[ni], acc[mi][ni], 0, 0, 0);              \
        __builtin_amdgcn_s_setprio(0);                                  \
    } while (0)

    // Prologue: stage tiles 0,1,2 (12 loads); wait tile 0 landed (8 in flight).
    STAGE(0); STAGE(1); STAGE(2);
    asm volatile("s_waitcnt vmcnt(8)" ::: "memory");
    asm volatile("s_barrier" ::: "memory");

    // Main loop: T = 0..123 (unroll 4 makes (T&3) buffer bases compile-time).
#pragma unroll 4
    for (int T = 0; T < NT - 4; ++T) {
        STAGE(T + 3);
        COMPUTE(T);
        asm volatile("s_waitcnt vmcnt(8)" ::: "memory");  // tile T+1 landed
        asm volatile("s_barrier" ::: "memory");
    }
    // T = 124: last stage (tile 127)
    STAGE(NT - 1);
    COMPUTE(NT - 4);
    asm volatile("s_waitcnt vmcnt(8)" ::: "memory");      // 125 landed
    asm volatile("s_barrier" ::: "memory");
    // Tail drain 8 -> 4 -> 0
    COMPUTE(NT - 3);
    asm volatile("s_waitcnt vmcnt(4)" ::: "memory");      // 126 landed
    asm volatile("s_barrier" ::: "memory");
    COMPUTE(NT - 2);
    asm volatile("s_waitcnt vmcnt(0)" ::: "memory");      // 127 landed
    asm volatile("s_barrier" ::: "memory");
    COMPUTE(NT - 1);

#undef STAGE
#undef COMPUTE

    // Epilogue: C/D layout col=lane&15, row=(lane>>4)*4+reg  [m89-verified]
    const int rb = (l >> 4) * 4;
    const int cl = l & 15;
#pragma unroll
    for (int ni = 0; ni < 4; ++ni) {
        const int   c  = n0 + wc * 64 + ni * 16 + cl;
        const float bv = bias[c];
#pragma unroll
        for (int mi = 0; mi < 8; ++mi) {
            const size_t base = (size_t)(m0 + wr * 128 + mi * 16 + rb) * N + c;
#pragma unroll
            for (int rg = 0; rg < 4; ++rg)
                C[base + (size_t)rg * N] = acc[mi][ni][rg] + bv;
        }
    }
}

// ---------------------------------------------------------------------------
extern "C" void kernel_launch(void* const* d_in, const int* in_sizes, int n_in,
                              void* d_out, int out_size, void* d_ws, size_t ws_size,
                              hipStream_t stream) {
    const float* x     = (const float*)d_in[0];   // [8,2048,4096] fp32
    const int*   Wq    = (const int*)d_in[1];     // [64,262144] int32
    const float* scale = (const float*)d_in[2];   // [1,262144]
    const float* zero  = (const float*)d_in[3];   // [1,262144]
    const float* bias  = (const float*)d_in[4];   // [4096]
    float* out = (float*)d_out;                   // [8,2048,4096] fp32

    const size_t wbytes = (size_t)OUT_F * IN_F * 2;   // 33.6 MB bf16 W
    const size_t xbytes = (size_t)MROWS * IN_F * 2;   // 134 MB bf16 x
    if (ws_size < wbytes + xbytes) {
        fprintf(stderr, "kernel_launch: ws_size=%zu < needed %zu — aborting\n",
                ws_size, wbytes + xbytes);
        return;
    }
    __bf16* Wb = (__bf16*)d_ws;
    __bf16* xb = (__bf16*)((char*)d_ws + wbytes);

    dequant_w<<<(OUT_F * IN_F / 4) / 256, 256, 0, stream>>>(Wq, scale, zero, Wb);
    convert_x<<<((size_t)MROWS * IN_F / 8) / 256, 256, 0, stream>>>(x, xb);

    gemm256<<<dim3((MROWS / 256) * (OUT_F / 256)), dim3(512), 0, stream>>>(
        xb, Wb, bias, out);
}

// Round 3
// 928.148 us; speedup vs baseline: 1.1746x; 1.0099x over previous
//
#include <hip/hip_runtime.h>
#include <cstdio>
#include <cstdint>
#include <cstddef>

#define AS_GLOBAL __attribute__((address_space(1)))
#define AS_LDS    __attribute__((address_space(3)))

typedef __bf16 bf16x8 __attribute__((ext_vector_type(8)));
typedef float  f32x4  __attribute__((ext_vector_type(4)));

constexpr int OUT_F = 4096;
constexpr int IN_F  = 4096;
constexpr int MROWS = 8 * 2048;   // B*S = 16384

// ---------------------------------------------------------------------------
// Kernel 1: dequantize W_q -> bf16 W[o][i]  (unchanged — verified)
// ---------------------------------------------------------------------------
__global__ void dequant_w(const int* __restrict__ Wq, const float* __restrict__ scale,
                          const float* __restrict__ zero, __bf16* __restrict__ Wb) {
    int t   = blockIdx.x * blockDim.x + threadIdx.x;
    int idx = t * 4;                       // flat index into W[o][i]
    int o   = idx >> 12;
    int i   = idx & 4095;
    int n   = ((o & 63) << 12) | i;        // group index
    size_t flat = ((size_t)(o >> 6) << 18) + (size_t)n;
    int4   q = *(const int4*)(Wq + flat);
    float4 z = *(const float4*)(zero + n);
    float4 s = *(const float4*)(scale + n);
    __bf16 r[4];
    r[0] = (__bf16)(((float)q.x - z.x) * s.x);
    r[1] = (__bf16)(((float)q.y - z.y) * s.y);
    r[2] = (__bf16)(((float)q.z - z.z) * s.z);
    r[3] = (__bf16)(((float)q.w - z.w) * s.w);
    *(uint2*)(Wb + idx) = *(const uint2*)r;
}

// ---------------------------------------------------------------------------
// Kernel 2: x fp32 -> bf16  (unchanged)
// ---------------------------------------------------------------------------
__global__ void convert_x(const float* __restrict__ x, __bf16* __restrict__ xb) {
    size_t t   = (size_t)blockIdx.x * blockDim.x + threadIdx.x;
    size_t idx = t * 8;
    float4 a = *(const float4*)(x + idx);
    float4 b = *(const float4*)(x + idx + 4);
    __bf16 r[8];
    r[0] = (__bf16)a.x; r[1] = (__bf16)a.y; r[2] = (__bf16)a.z; r[3] = (__bf16)a.w;
    r[4] = (__bf16)b.x; r[5] = (__bf16)b.y; r[6] = (__bf16)b.z; r[7] = (__bf16)b.w;
    *(uint4*)(xb + idx) = *(const uint4*)r;
}

// ---------------------------------------------------------------------------
// Kernel 3: C = A * B^T + bias, 256x256 tile, BK=64, 8 waves (2M x 4N),
// m201-style 4-phase-per-K-tile schedule (16 MFMA/phase), half-tile ring of
// 4 x 32KB LDS slots (A 16K + B 16K each; 128 KiB total).
//
// Per K-tile T (parity P=T&1; h0 slot=2P, h1 slot=2P+1):
//   ph0: read A-frags(h0)x8 + B n01(h0)x2 | STAGE A(T+1,h1) | bar | lgkm0 | 16 MFMA | bar
//   ph1: read B n23(h0)x2                 | STAGE B(T+1,h1) | bar | lgkm0 | 16 MFMA | vmcnt(8) bar
//   ph2: read A-frags(h1)x8 + B n01(h1)x2 | STAGE A(T+2,h0) | bar | lgkm0 | 16 MFMA | bar
//   ph3: read B n23(h1)x2                 | STAGE B(T+2,h0) | bar | lgkm0 | 16 MFMA | vmcnt(8) bar
// Halves staged 3 consumption-halves ahead; vmcnt(8) leaves 8 loads in
// flight across every barrier (never drains mid-loop). Publish audit:
//   (T,h1) published at T.ph1-end (its 4 loads issued T-1.ph0/ph1; 8 issued
//   since), read first at T.ph2.  (T+1,h0) published at T.ph3-end (issued
//   T-1.ph2/ph3), read first at T+1.ph0.  Ring overwrite: STAGE target's
//   last reader is >=2 barriers upstream.  Tail drains 8 -> 4 -> 0.
// LDS subtile swizzle unchanged (round-2-verified, 0 bank conflicts).
// ---------------------------------------------------------------------------
__device__ __forceinline__ void load16_to_lds(const void* g, void* lds) {
    __builtin_amdgcn_global_load_lds((AS_GLOBAL void*)g, (AS_LDS void*)lds, 16, 0, 0);
}

#define BAR   asm volatile("s_barrier" ::: "memory")
#define LGKM0 asm volatile("s_waitcnt lgkmcnt(0)" ::: "memory")
#define VM8   asm volatile("s_waitcnt vmcnt(8)" ::: "memory")
#define VM4   asm volatile("s_waitcnt vmcnt(4)" ::: "memory")
#define VMDRAIN asm volatile("s_waitcnt vmcnt(0)" ::: "memory")

__global__ __launch_bounds__(512, 2) void gemm256(
    const __bf16* __restrict__ A,   // [M][K]
    const __bf16* __restrict__ B,   // [N][K]
    const float*  __restrict__ bias,
    float*        __restrict__ C)   // [M][N]
{
    constexpr int K   = IN_F, N = OUT_F;
    constexpr int NT  = K / 64;                    // 64 K-tiles of BK=64
    __shared__ __align__(16) char smem[131072];    // 4 half-slots x 32 KB

    const int tid = threadIdx.x;
    const int l   = tid & 63;
    const int w   = tid >> 6;          // wave 0..7
    const int wr  = w >> 2;            // wave row 0..1  (128 rows each)
    const int wc  = w & 3;             // wave col 0..3  (64 cols each)

    // T1: bijective XCD swizzle (1024 blocks, 8 XCDs, n-fastest in-chunk).
    const int bid = blockIdx.x;
    const int wg  = (bid & 7) * 128 + (bid >> 3);
    const int n0  = (wg & 15) * 256;
    const int m0  = (wg >> 4) * 256;

    // Staging source (inverse-swizzled global addr; round-2-verified).
    // Wave w owns subtiles {2w, 2w+1} of A and of B in every half-slot.
    const int srow   = l >> 2;
    const int schunk = (l & 3) ^ ((l >> 3) & 3);
    const __bf16* sA0 = A + (size_t)(m0 + (w*2+0)*16 + srow) * K + schunk*8;
    const __bf16* sA1 = A + (size_t)(m0 + (w*2+1)*16 + srow) * K + schunk*8;
    const __bf16* sB0 = B + (size_t)(n0 + (w*2+0)*16 + srow) * K + schunk*8;
    const __bf16* sB1 = B + (size_t)(n0 + (w*2+1)*16 + srow) * K + schunk*8;
    const int dstA0 = (w*2+0)*1024, dstA1 = (w*2+1)*1024;
    const int dstB0 = 16384 + dstA0, dstB1 = 16384 + dstA1;

    // Fragment read offset (swizzled): lane holds X[row=l&15][k=(l>>4)*8+j]
    const int fr = l & 15, fg = l >> 4;
    const int in_off = fr*64 + ((fg ^ ((fr >> 1) & 3)) << 4);

    f32x4 acc[8][4] = {};
    bf16x8 aF[8], bF[2];

#define READ_A(sl) do { _Pragma("unroll")                                     \
    for (int mi = 0; mi < 8; ++mi)                                            \
        aF[mi] = *(const bf16x8*)(smem + (sl)*32768 + (wr*8 + mi)*1024 + in_off); } while (0)

#define READ_B(sl, nb) do {                                                   \
    bF[0] = *(const bf16x8*)(smem + (sl)*32768 + 16384 + (wc*4 + (nb)    )*1024 + in_off); \
    bF[1] = *(const bf16x8*)(smem + (sl)*32768 + 16384 + (wc*4 + (nb) + 1)*1024 + in_off); } while (0)

#define STAGE_A(sl, koff) do {                                                \
    load16_to_lds(sA0 + (koff), smem + (sl)*32768 + dstA0);                   \
    load16_to_lds(sA1 + (koff), smem + (sl)*32768 + dstA1); } while (0)

#define STAGE_B(sl, koff) do {                                                \
    load16_to_lds(sB0 + (koff), smem + (sl)*32768 + dstB0);                   \
    load16_to_lds(sB1 + (koff), smem + (sl)*32768 + dstB1); } while (0)

#define MFMA16(nb) do {                                                       \
    __builtin_amdgcn_s_setprio(1);                                            \
    _Pragma("unroll")                                                         \
    for (int mi = 0; mi < 8; ++mi) {                                          \
        acc[mi][(nb)  ] = __builtin_amdgcn_mfma_f32_16x16x32_bf16(aF[mi], bF[0], acc[mi][(nb)  ], 0, 0, 0); \
        acc[mi][(nb)+1] = __builtin_amdgcn_mfma_f32_16x16x32_bf16(aF[mi], bF[1], acc[mi][(nb)+1], 0, 0, 0); } \
    __builtin_amdgcn_s_setprio(0); } while (0)

    // Prologue: (0,h0)->slot0, (0,h1)->slot1, (1,h0)->slot2; publish (0,h0).
    STAGE_A(0, 0);  STAGE_B(0, 0);
    STAGE_A(1, 32); STAGE_B(1, 32);
    STAGE_A(2, 64); STAGE_B(2, 64);
    VM8; BAR;

    // Main loop: tile pair (T even, T+1). Full staging needs T+3 <= NT-1.
    for (int T = 0; T < NT - 3; T += 2) {
        const int kA = T * 64;
        // ---- tile T (parity 0): h0=slot0, h1=slot1 ----
        READ_A(0); READ_B(0, 0); STAGE_A(3, kA +  96); BAR; LGKM0; MFMA16(0); BAR;
        READ_B(0, 2);            STAGE_B(3, kA +  96); BAR; LGKM0; MFMA16(2); VM8; BAR;
        READ_A(1); READ_B(1, 0); STAGE_A(0, kA + 128); BAR; LGKM0; MFMA16(0); BAR;
        READ_B(1, 2);            STAGE_B(0, kA + 128); BAR; LGKM0; MFMA16(2); VM8; BAR;
        // ---- tile T+1 (parity 1): h0=slot2, h1=slot3 ----
        READ_A(2); READ_B(2, 0); STAGE_A(1, kA + 160); BAR; LGKM0; MFMA16(0); BAR;
        READ_B(2, 2);            STAGE_B(1, kA + 160); BAR; LGKM0; MFMA16(2); VM8; BAR;
        READ_A(3); READ_B(3, 0); STAGE_A(2, kA + 192); BAR; LGKM0; MFMA16(0); BAR;
        READ_B(3, 2);            STAGE_B(2, kA + 192); BAR; LGKM0; MFMA16(2); VM8; BAR;
    }
    // ---- tile NT-2 = 62 (parity 0): stage only (63,h1)->slot3 ----
    {
        const int kA = (NT - 2) * 64;
        READ_A(0); READ_B(0, 0); STAGE_A(3, kA + 96); BAR; LGKM0; MFMA16(0); BAR;
        READ_B(0, 2);            STAGE_B(3, kA + 96); BAR; LGKM0; MFMA16(2); VM8; BAR;
        READ_A(1); READ_B(1, 0);                      BAR; LGKM0; MFMA16(0); BAR;
        READ_B(1, 2);                                 BAR; LGKM0; MFMA16(2); VM4; BAR;
    }
    // ---- tile NT-1 = 63 (parity 1): no staging; drain ----
    {
        READ_A(2); READ_B(2, 0); BAR; LGKM0; MFMA16(0); BAR;
        READ_B(2, 2);            BAR; LGKM0; MFMA16(2); VMDRAIN; BAR;
        READ_A(3); READ_B(3, 0); BAR; LGKM0; MFMA16(0); BAR;
        READ_B(3, 2);            LGKM0; MFMA16(2);   // last phase: no trailing sync
    }

#undef READ_A
#undef READ_B
#undef STAGE_A
#undef STAGE_B
#undef MFMA16

    // Epilogue: C/D layout col=lane&15, row=(lane>>4)*4+reg  [m89-verified]
    const int rb = (l >> 4) * 4;
    const int cl = l & 15;
#pragma unroll
    for (int ni = 0; ni < 4; ++ni) {
        const int   c  = n0 + wc * 64 + ni * 16 + cl;
        const float bv = bias[c];
#pragma unroll
        for (int mi = 0; mi < 8; ++mi) {
            const size_t base = (size_t)(m0 + wr * 128 + mi * 16 + rb) * N + c;
#pragma unroll
            for (int rg = 0; rg < 4; ++rg)
                C[base + (size_t)rg * N] = acc[mi][ni][rg] + bv;
        }
    }
}

// ---------------------------------------------------------------------------
extern "C" void kernel_launch(void* const* d_in, const int* in_sizes, int n_in,
                              void* d_out, int out_size, void* d_ws, size_t ws_size,
                              hipStream_t stream) {
    const float* x     = (const float*)d_in[0];   // [8,2048,4096] fp32
    const int*   Wq    = (const int*)d_in[1];     // [64,262144] int32
    const float* scale = (const float*)d_in[2];   // [1,262144]
    const float* zero  = (const float*)d_in[3];   // [1,262144]
    const float* bias  = (const float*)d_in[4];   // [4096]
    float* out = (float*)d_out;                   // [8,2048,4096] fp32

    const size_t wbytes = (size_t)OUT_F * IN_F * 2;   // 33.6 MB bf16 W
    const size_t xbytes = (size_t)MROWS * IN_F * 2;   // 134 MB bf16 x
    if (ws_size < wbytes + xbytes) {
        fprintf(stderr, "kernel_launch: ws_size=%zu < needed %zu — aborting\n",
                ws_size, wbytes + xbytes);
        return;
    }
    __bf16* Wb = (__bf16*)d_ws;
    __bf16* xb = (__bf16*)((char*)d_ws + wbytes);

    dequant_w<<<(OUT_F * IN_F / 4) / 256, 256, 0, stream>>>(Wq, scale, zero, Wb);
    convert_x<<<((size_t)MROWS * IN_F / 8) / 256, 256, 0, stream>>>(x, xb);

    gemm256<<<dim3((MROWS / 256) * (OUT_F / 256)), dim3(512), 0, stream>>>(
        xb, Wb, bias, out);
}